// Round 1
// baseline (191.425 us; speedup 1.0000x reference)
//
#include <hip/hip_runtime.h>
#include <math.h>

#define SAMPLE_RATE 44100.0
#define R_PARAM 0.5
#define F_PARAM 1000.0

// ---------------------------------------------------------------------------
// Prologue: single thread builds the combined affine map from the 4 scalars.
// ws layout (floats): [0..15] Mc = M_inv@M_fwd (row-major),
//                     [16..19] va = M_inv@b_a, [20..23] vb = M_inv@b_1ma,
//                     [24] gain
// ---------------------------------------------------------------------------
__device__ void inv4x4(const double A[4][4], double Ainv[4][4]) {
    double M[4][8];
    for (int i = 0; i < 4; ++i) {
        for (int j = 0; j < 4; ++j) { M[i][j] = A[i][j]; M[i][4 + j] = (i == j) ? 1.0 : 0.0; }
    }
    for (int col = 0; col < 4; ++col) {
        int p = col;
        for (int r = col + 1; r < 4; ++r)
            if (fabs(M[r][col]) > fabs(M[p][col])) p = r;
        if (p != col)
            for (int j = 0; j < 8; ++j) { double t = M[col][j]; M[col][j] = M[p][j]; M[p][j] = t; }
        double d = 1.0 / M[col][col];
        for (int j = 0; j < 8; ++j) M[col][j] *= d;
        for (int r = 0; r < 4; ++r) {
            if (r == col) continue;
            double f = M[r][col];
            for (int j = 0; j < 8; ++j) M[r][j] -= f * M[col][j];
        }
    }
    for (int i = 0; i < 4; ++i)
        for (int j = 0; j < 4; ++j) Ainv[i][j] = M[i][4 + j];
}

__global__ void moog_prologue(const float* __restrict__ gf,
                              const float* __restrict__ gr,
                              const float* __restrict__ gain,
                              const float* __restrict__ alpha,
                              float* __restrict__ ws) {
    const double k  = 1.0 / SAMPLE_RATE;
    const double w  = 2.0 * M_PI * (double)gf[0] * F_PARAM;
    const double grv = (double)gr[0];
    const double al  = (double)alpha[0];
    const double gn  = (double)gain[0];

    double A[4][4] = {
        { -w, 0.0, 0.0, -4.0 * w * grv * R_PARAM },
        {  w,  -w, 0.0, 0.0 },
        { 0.0,  w,  -w, 0.0 },
        { 0.0, 0.0,  w,  -w }
    };

    double kA2[4][4];
    for (int i = 0; i < 4; ++i)
        for (int j = 0; j < 4; ++j) kA2[i][j] = 0.5 * k * A[i][j];

    // I - kA2*alpha
    double Mlhs[4][4];
    for (int i = 0; i < 4; ++i)
        for (int j = 0; j < 4; ++j)
            Mlhs[i][j] = ((i == j) ? 1.0 : 0.0) - kA2[i][j] * al;

    double Minv[4][4];
    inv4x4(Mlhs, Minv);

    // M_fwd = I + 2*kA2 - kA2*alpha = I + kA2*(2 - alpha)
    double Mfwd[4][4];
    for (int i = 0; i < 4; ++i)
        for (int j = 0; j < 4; ++j)
            Mfwd[i][j] = ((i == j) ? 1.0 : 0.0) + kA2[i][j] * (2.0 - al);

    // Mc = Minv @ Mfwd
    double Mc[4][4];
    for (int i = 0; i < 4; ++i)
        for (int j = 0; j < 4; ++j) {
            double s = 0.0;
            for (int m = 0; m < 4; ++m) s += Minv[i][m] * Mfwd[m][j];
            Mc[i][j] = s;
        }

    // b vectors: kb2 = k*Bv/2 with Bv = [w,0,0,0]^T
    double kb2_0 = 0.5 * k * w;
    double ba0  = kb2_0 * al;                 // b_a   = kb2*alpha
    double b1m0 = kb2_0 * (1.0 - 0.5 * al);   // b_1ma = kb2*(1 - alpha/2)

    // va = Minv @ b_a (only first component of b nonzero), vb likewise
    for (int i = 0; i < 4; ++i) {
        for (int j = 0; j < 4; ++j) ws[4 * i + j] = (float)Mc[i][j];
        ws[16 + i] = (float)(Minv[i][0] * ba0);
        ws[20 + i] = (float)(Minv[i][0] * b1m0);
    }
    ws[24] = (float)gn;
}

// ---------------------------------------------------------------------------
// Main kernel: one thread per sample.
// out layout: [0,B) = y_n ; [B,5B) = x_n (4 per sample) ; [5B,6B) = u_n copy
// ---------------------------------------------------------------------------
__global__ __launch_bounds__(256) void moog_main(
        const float*  __restrict__ u_n,
        const float4* __restrict__ x_n1,
        const float*  __restrict__ u_n1,
        const float*  __restrict__ ws,
        float* __restrict__ out,
        int B) {
    __shared__ float c[25];
    int t = threadIdx.x;
    if (t < 25) c[t] = ws[t];
    __syncthreads();

    int i = blockIdx.x * blockDim.x + t;
    if (i >= B) return;

    float4 x = x_n1[i];
    float u  = u_n[i];
    float u1 = u_n1[i];

    float r0 = c[0]  * x.x + c[1]  * x.y + c[2]  * x.z + c[3]  * x.w + c[16] * u + c[20] * u1;
    float r1 = c[4]  * x.x + c[5]  * x.y + c[6]  * x.z + c[7]  * x.w + c[17] * u + c[21] * u1;
    float r2 = c[8]  * x.x + c[9]  * x.y + c[10] * x.z + c[11] * x.w + c[18] * u + c[22] * u1;
    float r3 = c[12] * x.x + c[13] * x.y + c[14] * x.z + c[15] * x.w + c[19] * u + c[23] * u1;

    out[i] = c[24] * r3;                         // y_n
    float4* ox = (float4*)(out + B);             // x_n block (16-byte aligned: B*4 bytes)
    ox[i] = make_float4(r0, r1, r2, r3);
    out[5 * (size_t)B + i] = u;                  // u_n passthrough
}

extern "C" void kernel_launch(void* const* d_in, const int* in_sizes, int n_in,
                              void* d_out, int out_size, void* d_ws, size_t ws_size,
                              hipStream_t stream) {
    const float* u_n   = (const float*)d_in[0];
    const float* x_n1  = (const float*)d_in[1];
    const float* u_n1  = (const float*)d_in[2];
    const float* gf    = (const float*)d_in[3];
    const float* gr    = (const float*)d_in[4];
    const float* gain  = (const float*)d_in[5];
    const float* alpha = (const float*)d_in[6];

    int B = in_sizes[0];
    float* ws = (float*)d_ws;

    moog_prologue<<<1, 1, 0, stream>>>(gf, gr, gain, alpha, ws);

    int block = 256;
    int grid = (B + block - 1) / block;
    moog_main<<<grid, block, 0, stream>>>(u_n, (const float4*)x_n1, u_n1, ws,
                                          (float*)d_out, B);
}